// Round 1
// 213.753 us; speedup vs baseline: 1.0192x; 1.0192x over previous
//
#include <hip/hip_runtime.h>
#include <math.h>

// DCT encoder, separable form. kernels[k] = outer(cv_k, cu_k) with
// cv[i]=cos((2i+1)v pi/64) on ROWS (i), cu[j] on COLUMNS (j)  [meshgrid 'xy'].
// Stage1 contracts y=cols with freq f1==u; stage2 contracts x=rows with f2==v.
// R5: channel-split grid (b,m,c) -> 1536 blocks = 4 blocks/CU (was 2, grid-capped);
// 1 syncthreads/block (was 6); T2 reordered so each thread prefetches its 8
// {k,scale} entries as 4x16B loads instead of dependent 4B loads per store.
// c varies at stride 16 in blockIdx so the 3 channel-blocks of one strip land on
// the same XCD back-to-back (L2 reuse of the 196KB input strip). m-pair write-
// merge swizzle (g <-> g+8) preserved.

typedef __bf16 bf16x8 __attribute__((ext_vector_type(8)));
typedef float  f32x4  __attribute__((ext_vector_type(4)));

#define PI_F 3.14159265358979323846f

__device__ __forceinline__ unsigned short f2bf(float f) {
    union { float f; unsigned u; } v; v.f = f;
    unsigned u = v.u;
    u += 0x7fffu + ((u >> 16) & 1u);   // round-to-nearest-even
    return (unsigned short)(u >> 16);
}

// ---- K0: cos table (bf16) + fused {k, scale} table --------------------------
// kern[k][i][j] = cos((2j+1)u pi/64) * cos((2i+1)v pi/64), k sorted by |(v,u)|.
// v from K[1][0]/K[0][0] = 4cos^2(v pi/64)-3; u from K[0][1]/K[0][0].
// T2r layout: [(u*4 + quad)*8 + uh*4 + r] where v = uh*16 + quad*4 + r,
// so stage-2's (f1=u, quad) thread reads its 8 entries as one 64B run.
__global__ __launch_bounds__(256) void setup_kernel(const float* __restrict__ kern,
                                                    const float* __restrict__ factors,
                                                    unsigned short* __restrict__ Cbf,
                                                    int2* __restrict__ T2) {
    int k = blockIdx.x * 256 + threadIdx.x;   // 0..1023
    int i = k & 31, t = k >> 5;
    Cbf[k] = f2bf(cosf((float)((2 * i + 1) * t) * (PI_F / 64.f)));

    float k00 = kern[(size_t)k * 1024];              // cv[0]*cu[0] > 0 always
    float rv  = kern[(size_t)k * 1024 + 32] / k00;   // -> v
    float ru  = kern[(size_t)k * 1024 + 1]  / k00;   // -> u
    float cv2 = fminf(fmaxf((rv + 3.f) * 0.25f, 0.f), 1.f);
    float cu2 = fminf(fmaxf((ru + 3.f) * 0.25f, 0.f), 1.f);
    int v = __float2int_rn(acosf(sqrtf(cv2)) * (64.f / PI_F));
    int u = __float2int_rn(acosf(sqrtf(cu2)) * (64.f / PI_F));
    float s = factors[k] * (2.f / 32.f);
    int vq = (v >> 2) & 3, vh = v >> 4, vr = v & 3;
    T2[(u * 4 + vq) * 8 + vh * 4 + vr] = make_int2(k, __float_as_int(s));
}

// ---- fused kernel: one block per (b, m, c) strip of 16 DCT blocks -----------
// Stage1: T[f1][n][x] = sum_y C[f1][y] * ycbcr[c][m*32+x][n*32+y]   (MFMA, K=32)
// Stage2: out[bc][k(f2,f1)][m*16+n] = s * sum_x C[f2][x] * T[f1][n][x]
// LDS T row (f1,n): 80 B (32 bf16 + 16 pad), f1-stride 1280 B -> 40 KB
// -> exactly 4 blocks/CU (160 KB LDS).
__global__ __launch_bounds__(512, 8) void dct_fused(const float* __restrict__ rgb,
                                                    const unsigned short* __restrict__ Cbf,
                                                    const int2* __restrict__ T2,
                                                    float* __restrict__ out) {
    __shared__ __align__(16) unsigned char Tls[32 * 1280];   // 40 KB

    const int tid  = threadIdx.x;
    const int lane = tid & 63;
    const int w    = tid >> 6;        // wave 0..7, owns x = w*4..w*4+3
    const int quad = lane >> 4;
    const int l15  = lane & 15;
    // blockIdx decode: g = bc*16 + loc, bc = b*3 + c (c at stride 16 -> same XCD
    // for a strip's 3 channel-blocks), loc -> m with the g<->g+8 pair swizzle
    // so m=2t / 2t+1 half-lines merge to one 128B line in that XCD's L2.
    const int g    = blockIdx.x;
    const int bc   = g >> 4;          // 0..95
    const int b    = bc / 3;
    const int c    = bc - b * 3;
    const int loc  = g & 15;
    const int m    = ((loc & 7) << 1) | (loc >> 3);

    // A-operand frags (both stages): A[row=l15][k=quad*8+j] = C[row][pos]
    union { bf16x8 v; unsigned short s[8]; } af0, af1;
    af0.v = *(const bf16x8*)(Cbf + l15 * 32 + quad * 8);
    af1.v = *(const bf16x8*)(Cbf + (16 + l15) * 32 + quad * 8);

    const f32x4 zero = {0.f, 0.f, 0.f, 0.f};

    // channel conversion folded to one dot product: val = ar*R + ag*G + ab*B + ao
    // c=0: 2*(.299R+.587G+.114B)-1
    // c=1: 1.128*(B - Y)   c=2: 1.426*(R - Y)
    float ar, ag, ab, ao;
    if (c == 0)      { ar =  0.598f;     ag =  1.174f;     ab =  0.228f;     ao = -1.f; }
    else if (c == 1) { ar = -0.337272f;  ag = -0.662136f;  ab =  0.999408f;  ao =  0.f; }
    else             { ar =  0.999626f;  ag = -0.837062f;  ab = -0.162564f;  ao =  0.f; }

    // ---- stage 1a: load rgb, convert this block's channel (16 VGPR of frags) --
    bf16x8 fr[4];   // [xi]
    const float* rbase = rgb + (size_t)b * 786432 + (size_t)l15 * 32 + (size_t)quad * 8;
#pragma unroll
    for (int xi = 0; xi < 4; ++xi) {
        const int x = w * 4 + xi;
        const float* p = rbase + (size_t)(m * 32 + x) * 512;
        float4 R0 = *(const float4*)(p);
        float4 R1 = *(const float4*)(p + 4);
        float4 G0 = *(const float4*)(p + 262144);
        float4 G1 = *(const float4*)(p + 262148);
        float4 B0 = *(const float4*)(p + 524288);
        float4 B1 = *(const float4*)(p + 524292);
        float R[8]  = {R0.x, R0.y, R0.z, R0.w, R1.x, R1.y, R1.z, R1.w};
        float G[8]  = {G0.x, G0.y, G0.z, G0.w, G1.x, G1.y, G1.z, G1.w};
        float Bv[8] = {B0.x, B0.y, B0.z, B0.w, B1.x, B1.y, B1.z, B1.w};
        union { bf16x8 v; unsigned short s[8]; } f;
#pragma unroll
        for (int e = 0; e < 8; ++e) {
            float val = ar * R[e] + ag * G[e] + ab * Bv[e] + ao;
            f.s[e] = f2bf(val);
        }
        fr[xi] = f.v;
    }

    // ---- stage 1b: MFMAs (transient acc) -> LDS scatter ----
#pragma unroll
    for (int fh = 0; fh < 2; ++fh) {
        f32x4 dd[4];
#pragma unroll
        for (int xi = 0; xi < 4; ++xi)
            dd[xi] = __builtin_amdgcn_mfma_f32_16x16x32_bf16(
                fh ? af1.v : af0.v, fr[xi], zero, 0, 0, 0);
        // scatter: T[f1][n=l15][x-chunk w], rows f1 = fh*16+quad*4+r
#pragma unroll
        for (int r = 0; r < 4; ++r) {
            const int f1 = fh * 16 + quad * 4 + r;
            ushort4 pk;
            pk.x = f2bf(dd[0][r]);
            pk.y = f2bf(dd[1][r]);
            pk.z = f2bf(dd[2][r]);
            pk.w = f2bf(dd[3][r]);
            *(ushort4*)(Tls + f1 * 1280 + l15 * 80 + w * 8) = pk;
        }
    }
    __syncthreads();

    // ---- stage 2: LDS -> MFMA -> scattered stores (T2 entries prefetched) ----
    const size_t obase = (size_t)bc * 262144 + (size_t)m * 16 + (size_t)l15;
#pragma unroll
    for (int i = 0; i < 4; ++i) {
        const int f1 = w * 4 + i;   // stage-1 freq == u (column freq)
        union { int4 q[4]; int2 e[8]; } tt;
        const int4* tp = (const int4*)(T2 + ((f1 * 4 + quad) << 3));
        tt.q[0] = tp[0]; tt.q[1] = tp[1]; tt.q[2] = tp[2]; tt.q[3] = tp[3];
        bf16x8 bfr = *(const bf16x8*)(Tls + f1 * 1280 + l15 * 80 + quad * 16);
#pragma unroll
        for (int uh = 0; uh < 2; ++uh) {
            f32x4 d2 = __builtin_amdgcn_mfma_f32_16x16x32_bf16(
                uh ? af1.v : af0.v, bfr, zero, 0, 0, 0);
#pragma unroll
            for (int r = 0; r < 4; ++r) {
                int2 ks = tt.e[uh * 4 + r];   // {k, scale} for f2 = uh*16+quad*4+r
                out[obase + (size_t)ks.x * 256] = d2[r] * __int_as_float(ks.y);
            }
        }
    }
}

extern "C" void kernel_launch(void* const* d_in, const int* in_sizes, int n_in,
                              void* d_out, int out_size, void* d_ws, size_t ws_size,
                              hipStream_t stream) {
    const float* rgb     = (const float*)d_in[0];  // (32,3,512,512)
    const float* kern    = (const float*)d_in[1];  // (1024,32,32)
    const float* factors = (const float*)d_in[2];  // (1024,)
    float* out = (float*)d_out;                    // (32,3072,16,16)

    unsigned short* Cbf = (unsigned short*)d_ws;          // 2 KB
    int2* T2 = (int2*)((char*)d_ws + 8192);               // 8 KB

    setup_kernel<<<4, 256, 0, stream>>>(kern, factors, Cbf, T2);
    dct_fused<<<1536, 512, 0, stream>>>(rgb, Cbf, T2, out);
}